// Round 5
// baseline (49.656 us; speedup 1.0000x reference)
//
#include <hip/hip_runtime.h>

#define NB 32
#define NK 8
#define IN_DIM 512
#define DLAT 128
#define DTOT 1024
#define ZS 516   // padded z row stride (floats): bank spread, no conflicts
#define PS 132   // padded psi row stride

// ---------------------------------------------------------------------------
// Kernel 1: one block per batch (32 blocks x 1024 threads).
// Thread (s = tid&7, o = tid>>3) computes the FULL 512-elem dot for
// psi[s][o] itself: no cross-lane reduction at all. W row o is read by the
// 8 lanes of the 8 shots at the same address (hardware broadcast), so W is
// fetched exactly once per block. z lives in padded LDS (conflict-free
// 8-unique-address broadcast reads). All reductions are shallow LDS trees.
// ---------------------------------------------------------------------------
__global__ __launch_bounds__(1024) void qsfm_avec(
    const float* __restrict__ z, const float* __restrict__ t,
    const float* __restrict__ W_proj, const float* __restrict__ b_proj,
    const float* __restrict__ W1, const float* __restrict__ b1,
    const float* __restrict__ W2, const float* __restrict__ b2,
    float* __restrict__ a_out, float* __restrict__ diag_out)
{
    __shared__ float zs[NK * ZS];      // staged z, padded
    __shared__ float sq[DTOT];         // reduction scratch
    __shared__ float psi_s[NK * PS];   // normalized state, padded
    __shared__ float mlp[DLAT];        // per-unit MLP terms
    __shared__ float lam16[16];
    __shared__ float norm2[NK];
    __shared__ float f_s[8];
    __shared__ float lam_sh, n2_sh;

    const int b = blockIdx.x;
    const int tid = threadIdx.x;

    // ---- stage z (8 shots x 512 floats), coalesced, padded stride
    {
        const float4 v = ((const float4*)(z + (size_t)b * NK * IN_DIM))[tid];
        const int sh = tid >> 7, pos = tid & 127;
        *(float4*)(zs + sh * ZS + pos * 4) = v;
    }
    // ---- MLP per-unit terms (independent of z; no barrier needed yet)
    if (tid < DLAT) {
        const float h = t[b] * W1[tid] + b1[tid];
        mlp[tid] = W2[tid] * (h / (1.f + expf(-h)));   // W2 * SiLU(h)
    }
    __syncthreads();

    // ---- projection: thread owns (shot, o); 4 independent FMA chains
    const int s = tid & 7, o = tid >> 3;
    float4 acc = {0.f, 0.f, 0.f, 0.f};
    {
        const float4* __restrict__ wr = (const float4*)(W_proj + (size_t)o * IN_DIM);
        const float* zrow = zs + s * ZS;
        #pragma unroll 8
        for (int j = 0; j < IN_DIM / 4; ++j) {
            const float4 w4 = wr[j];
            const float4 z4 = *(const float4*)(zrow + j * 4);
            acc.x += w4.x * z4.x; acc.y += w4.y * z4.y;
            acc.z += w4.z * z4.z; acc.w += w4.w * z4.w;
        }
    }
    const float psi = (acc.x + acc.y) + (acc.z + acc.w) + b_proj[o];

    // ---- per-shot ||psi||^2: s-preserving LDS tree (stride keeps tid%8)
    sq[tid] = psi * psi;
    __syncthreads();
    if (tid < 512) sq[tid] += sq[tid + 512];
    __syncthreads();
    if (tid < 256) sq[tid] += sq[tid + 256];
    __syncthreads();
    if (tid < 128) sq[tid] += sq[tid + 128];
    __syncthreads();
    if (tid < 64)  sq[tid] += sq[tid + 64];
    // lam partials in parallel with the last tree level (mlp[] is complete)
    if (tid >= 64 && tid < 80) {
        const int q = tid - 64;
        float v = 0.f;
        #pragma unroll
        for (int u = 0; u < 8; ++u) v += mlp[q * 8 + u];
        lam16[q] = v;
    }
    __syncthreads();
    if (tid < NK) {                    // finish shot norms: sum 8 strided
        float v = 0.f;
        #pragma unroll
        for (int u = 0; u < 8; ++u) v += sq[tid + u * 8];
        norm2[tid] = v;
    }
    if (tid == 32) {                   // finish lambda
        float v = 0.f;
        #pragma unroll
        for (int u = 0; u < 16; ++u) v += lam16[u];
        lam_sh = tanhf(v + b2[0]) * 0.1f;
    }
    __syncthreads();

    // ---- normalize own psi (register), store to LDS state; circulant coefs
    psi_s[s * PS + o] =
        psi / fmaxf(sqrtf(norm2[s]), 1e-8f) * 0.35355339059327373f; // 1/sqrt8
    if (tid < 8) {
        // E = exp(-lam*H_idx), C8 circulant: f(d) = 1/8 sum_m
        //   exp(-2 lam cos(pi m/4)) cos(pi m d/4)
        const float c4[8] = {1.f, 0.70710678118654752f, 0.f, -0.70710678118654752f,
                             -1.f, -0.70710678118654752f, 0.f, 0.70710678118654752f};
        const float lam = lam_sh;
        float a8 = 0.f;
        #pragma unroll
        for (int m = 0; m < 8; ++m)
            a8 += expf(-2.f * lam * c4[m]) * c4[(m * tid) & 7];
        f_s[tid] = 0.125f * a8;
    }
    __syncthreads();

    // ---- y = kron(E, I_128) @ state  (conflict-free: oo consecutive)
    const int k = tid >> 7, oo = tid & 127;
    float y = 0.f;
    #pragma unroll
    for (int kp = 0; kp < NK; ++kp)
        y += f_s[(k - kp) & 7] * psi_s[kp * PS + oo];

    // ---- ||y||^2: full LDS tree to one value
    sq[tid] = y * y;
    __syncthreads();
    if (tid < 512) sq[tid] += sq[tid + 512];
    __syncthreads();
    if (tid < 256) sq[tid] += sq[tid + 256];
    __syncthreads();
    if (tid < 128) sq[tid] += sq[tid + 128];
    __syncthreads();
    if (tid < 64)  sq[tid] += sq[tid + 64];
    __syncthreads();
    if (tid == 0) {
        float v = 0.f;
        #pragma unroll
        for (int u = 0; u < 8; ++u) v += (sq[u] + sq[u + 8]) + (sq[u + 16] + sq[u + 24])
                                       + (sq[u + 32] + sq[u + 40]) + (sq[u + 48] + sq[u + 56]);
        n2_sh = v;
    }
    __syncthreads();

    // ---- epilogue algebra: out[i][j] = a_i a_j + delta_ij * 1e-7/tr2,
    //      a = y / sqrt(n2c*tr2), tr2 = n2/n2c + 1024e-7
    const float n2  = n2_sh;
    const float n2c = fmaxf(n2, 1e-8f);
    const float tr2 = n2 / n2c + (float)DTOT * 1e-7f;
    const float sc  = 1.f / sqrtf(n2c * tr2);
    a_out[b * DTOT + tid] = y * sc;
    if (tid == 0) diag_out[b] = 1e-7f / tr2;
}

// ---------------------------------------------------------------------------
// Kernel 2: out[b,i,j] = a[b,i]*a[b,j] (+ diag[b] on the diagonal).
// Pure streaming write of 128 MB; a (128 KB) stays L2-resident. (~12 us)
// ---------------------------------------------------------------------------
__global__ __launch_bounds__(256) void qsfm_outer(
    const float* __restrict__ a, const float* __restrict__ diag,
    float4* __restrict__ out)
{
    const int total4 = NB * DTOT * (DTOT / 4);     // 8388608
    const int stride = gridDim.x * blockDim.x;
    for (int idx4 = blockIdx.x * blockDim.x + threadIdx.x; idx4 < total4;
         idx4 += stride) {
        const int j4 = idx4 & (DTOT / 4 - 1);      // float4 col
        const int i  = (idx4 >> 8) & (DTOT - 1);   // row
        const int b  = idx4 >> 18;                 // / (1024*256)
        const float ai = a[b * DTOT + i];
        const float4 aj = *(const float4*)(a + b * DTOT + j4 * 4);
        float4 v;
        v.x = ai * aj.x; v.y = ai * aj.y; v.z = ai * aj.z; v.w = ai * aj.w;
        const int dj = i - j4 * 4;
        if (dj >= 0 && dj < 4) {
            const float dd = diag[b];
            if      (dj == 0) v.x += dd;
            else if (dj == 1) v.y += dd;
            else if (dj == 2) v.z += dd;
            else              v.w += dd;
        }
        out[idx4] = v;
    }
}

extern "C" void kernel_launch(void* const* d_in, const int* in_sizes, int n_in,
                              void* d_out, int out_size, void* d_ws, size_t ws_size,
                              hipStream_t stream) {
    (void)in_sizes; (void)n_in; (void)out_size; (void)ws_size;
    const float* z  = (const float*)d_in[0];
    const float* t  = (const float*)d_in[1];
    const float* Wp = (const float*)d_in[2];
    const float* bp = (const float*)d_in[3];
    const float* W1 = (const float*)d_in[4];
    const float* b1 = (const float*)d_in[5];
    const float* W2 = (const float*)d_in[6];
    const float* b2 = (const float*)d_in[7];

    float* ws   = (float*)d_ws;
    float* a    = ws;              // NB*DTOT floats
    float* diag = ws + NB * DTOT;  // NB floats

    qsfm_avec<<<NB, 1024, 0, stream>>>(z, t, Wp, bp, W1, b1, W2, b2, a, diag);
    qsfm_outer<<<2048, 256, 0, stream>>>(a, diag, (float4*)d_out);
}

// Round 6
// 40.581 us; speedup vs baseline: 1.2236x; 1.2236x over previous
//
#include <hip/hip_runtime.h>

#define NB 32
#define NK 8
#define IN_DIM 512
#define DLAT 128
#define DTOT 1024

// ---------------------------------------------------------------------------
// Kernel P: one block per shot (256 blocks x 512 threads).
// Thread (o = tid>>2, q = tid&3) computes a 128-elem quarter-dot of
// psi[shot][o] -- 32 float4 FMA iterations, no cross-lane ops in the hot
// loop. z quarters live in LDS at padded stride 132 (conflict-free).
// ---------------------------------------------------------------------------
__global__ __launch_bounds__(512) void qsfm_proj(
    const float* __restrict__ z, const float* __restrict__ W_proj,
    const float* __restrict__ b_proj, float* __restrict__ psi_out)
{
    __shared__ float zs[4 * 132];      // 4 quarters x 128, padded
    __shared__ float pp[DLAT * 4];     // per-(o,q) partials
    __shared__ float wsum[2];

    const int shot = blockIdx.x;       // b*NK + k
    const int tid  = threadIdx.x;

    if (tid < 128) {
        const float4 v = ((const float4*)(z + (size_t)shot * IN_DIM))[tid];
        const int q = tid >> 5, e = (tid & 31) * 4;
        *(float4*)(zs + q * 132 + e) = v;
    }
    __syncthreads();

    {
        const int o = tid >> 2, q = tid & 3;
        const float4* __restrict__ wr =
            (const float4*)(W_proj + (size_t)o * IN_DIM + q * 128);
        const float* zq = zs + q * 132;
        float4 acc = {0.f, 0.f, 0.f, 0.f};
        #pragma unroll 8
        for (int j = 0; j < 32; ++j) {
            const float4 w4 = wr[j];
            const float4 z4 = *(const float4*)(zq + j * 4);
            acc.x += w4.x * z4.x; acc.y += w4.y * z4.y;
            acc.z += w4.z * z4.z; acc.w += w4.w * z4.w;
        }
        pp[tid] = (acc.x + acc.y) + (acc.z + acc.w);
    }
    __syncthreads();

    float psi = 0.f;
    if (tid < 128) {
        const float4 p4 = ((const float4*)pp)[tid];
        psi = (p4.x + p4.y) + (p4.z + p4.w) + b_proj[tid];
        float s = psi * psi;                 // ||psi||^2, 2 full waves
        #pragma unroll
        for (int m = 32; m; m >>= 1) s += __shfl_xor(s, m);
        if ((tid & 63) == 0) wsum[tid >> 6] = s;
    }
    __syncthreads();
    if (tid < 128) {
        const float n2 = wsum[0] + wsum[1];
        psi_out[shot * DLAT + tid] =
            psi / fmaxf(sqrtf(n2), 1e-8f) * 0.35355339059327373f; // 1/sqrt(8)
    }
}

// ---------------------------------------------------------------------------
// Kernel M: one block per batch (32 x 256). Fully parallel: MLP partials via
// wave reduce, circulant mix in float4, ||y||^2 via wave reduce.
// ---------------------------------------------------------------------------
__global__ __launch_bounds__(256) void qsfm_mix(
    const float* __restrict__ t,
    const float* __restrict__ W1, const float* __restrict__ b1,
    const float* __restrict__ W2, const float* __restrict__ b2,
    const float* __restrict__ psi_norm,
    float* __restrict__ a_out, float* __restrict__ diag_out)
{
    __shared__ float ps[NK * 132];     // state, padded stride 132
    __shared__ float lamp[2];
    __shared__ float f_s[8];
    __shared__ float npart[4];

    const int b = blockIdx.x;
    const int tid = threadIdx.x;
    const int lane = tid & 63, w = tid >> 6;
    const int k = tid >> 5;            // shot of this thread's 4 elems
    const int e = (tid & 31) * 4;      // col base

    {   // stage state
        const float4 pv = ((const float4*)(psi_norm + (size_t)b * DTOT))[tid];
        *(float4*)(ps + k * 132 + e) = pv;
    }
    if (tid < 128) {                   // MLP partials, 2 full waves
        const float h = t[b] * W1[tid] + b1[tid];
        float ml = W2[tid] * (h / (1.f + expf(-h)));
        #pragma unroll
        for (int m = 32; m; m >>= 1) ml += __shfl_xor(ml, m);
        if (lane == 0) lamp[w] = ml;
    }
    __syncthreads();
    if (tid < 8) {
        // E = exp(-lam*H_idx): C8 circulant,
        // f(d) = 1/8 sum_m exp(-2 lam cos(pi m/4)) cos(pi m d/4)
        const float lam = tanhf(lamp[0] + lamp[1] + b2[0]) * 0.1f;
        const float c4[8] = {1.f, 0.70710678118654752f, 0.f, -0.70710678118654752f,
                             -1.f, -0.70710678118654752f, 0.f, 0.70710678118654752f};
        float a8 = 0.f;
        #pragma unroll
        for (int m = 0; m < 8; ++m)
            a8 += expf(-2.f * lam * c4[m]) * c4[(m * tid) & 7];
        f_s[tid] = 0.125f * a8;
    }
    __syncthreads();

    // y = kron(E, I_128) @ state, 4 elems per thread (float4)
    float4 y4 = {0.f, 0.f, 0.f, 0.f};
    #pragma unroll
    for (int kp = 0; kp < NK; ++kp) {
        const float fc = f_s[(k - kp) & 7];
        const float4 p4 = *(const float4*)(ps + kp * 132 + e);
        y4.x += fc * p4.x; y4.y += fc * p4.y;
        y4.z += fc * p4.z; y4.w += fc * p4.w;
    }
    {
        float s = (y4.x * y4.x + y4.y * y4.y) + (y4.z * y4.z + y4.w * y4.w);
        #pragma unroll
        for (int m = 32; m; m >>= 1) s += __shfl_xor(s, m);
        if (lane == 0) npart[w] = s;
    }
    __syncthreads();

    // out[i][j] = a_i a_j + delta_ij*1e-7/tr2; a = y/sqrt(n2c*tr2)
    const float n2  = (npart[0] + npart[1]) + (npart[2] + npart[3]);
    const float n2c = fmaxf(n2, 1e-8f);
    const float tr2 = n2 / n2c + (float)DTOT * 1e-7f;
    const float sc  = 1.f / sqrtf(n2c * tr2);
    float4 av;
    av.x = y4.x * sc; av.y = y4.y * sc; av.z = y4.z * sc; av.w = y4.w * sc;
    ((float4*)(a_out + (size_t)b * DTOT))[tid] = av;
    if (tid == 0) diag_out[b] = 1e-7f / tr2;
}

// ---------------------------------------------------------------------------
// Kernel O: out[b,i,j] = a[b,i]*a[b,j] (+ diag[b] on the diagonal).
// Pure streaming write of 128 MB; a (128 KB) stays L2-resident.
// ---------------------------------------------------------------------------
__global__ __launch_bounds__(256) void qsfm_outer(
    const float* __restrict__ a, const float* __restrict__ diag,
    float4* __restrict__ out)
{
    const int total4 = NB * DTOT * (DTOT / 4);     // 8388608
    const int stride = gridDim.x * blockDim.x;
    for (int idx4 = blockIdx.x * blockDim.x + threadIdx.x; idx4 < total4;
         idx4 += stride) {
        const int j4 = idx4 & (DTOT / 4 - 1);      // float4 col
        const int i  = (idx4 >> 8) & (DTOT - 1);   // row
        const int b  = idx4 >> 18;                 // / (1024*256)
        const float ai = a[b * DTOT + i];
        const float4 aj = *(const float4*)(a + b * DTOT + j4 * 4);
        float4 v;
        v.x = ai * aj.x; v.y = ai * aj.y; v.z = ai * aj.z; v.w = ai * aj.w;
        const int dj = i - j4 * 4;
        if (dj >= 0 && dj < 4) {
            const float dd = diag[b];
            if      (dj == 0) v.x += dd;
            else if (dj == 1) v.y += dd;
            else if (dj == 2) v.z += dd;
            else              v.w += dd;
        }
        out[idx4] = v;
    }
}

extern "C" void kernel_launch(void* const* d_in, const int* in_sizes, int n_in,
                              void* d_out, int out_size, void* d_ws, size_t ws_size,
                              hipStream_t stream) {
    (void)in_sizes; (void)n_in; (void)out_size; (void)ws_size;
    const float* z  = (const float*)d_in[0];
    const float* t  = (const float*)d_in[1];
    const float* Wp = (const float*)d_in[2];
    const float* bp = (const float*)d_in[3];
    const float* W1 = (const float*)d_in[4];
    const float* b1 = (const float*)d_in[5];
    const float* W2 = (const float*)d_in[6];
    const float* b2 = (const float*)d_in[7];

    float* ws       = (float*)d_ws;
    float* psi_norm = ws;                        // NB*DTOT floats
    float* a        = psi_norm + NB * DTOT;      // NB*DTOT floats
    float* diag     = a + NB * DTOT;             // NB floats

    qsfm_proj<<<NB * NK, 512, 0, stream>>>(z, Wp, bp, psi_norm);
    qsfm_mix<<<NB, 256, 0, stream>>>(t, W1, b1, W2, b2, psi_norm, a, diag);
    qsfm_outer<<<2048, 256, 0, stream>>>(a, diag, (float4*)d_out);
}

// Round 7
// 36.446 us; speedup vs baseline: 1.3624x; 1.1134x over previous
//
#include <hip/hip_runtime.h>

#define NB 32
#define NK 8
#define IN_DIM 512
#define DLAT 128
#define DTOT 1024

// ---------------------------------------------------------------------------
// Kernel P: one block per shot (256 blocks x 512 threads = 8 waves).
// z row (512 f) lives in 4 float4 REGISTERS per lane (idx m, m+32, m+64,
// m+96 -> coalesced). Wave w owns rows [w*16, w*16+16), processed 2 rows per
// pass in 32-lane halves: W reads coalesced (same f4 indices as z), dot in
// registers, 5-step __shfl_xor within the half. Per-CU shuffle count is 320
// (vs 6144 in the R4 avec that measured ~35 us).
// ---------------------------------------------------------------------------
__global__ __launch_bounds__(512) void qsfm_proj(
    const float* __restrict__ z, const float* __restrict__ W_proj,
    const float* __restrict__ b_proj, float* __restrict__ psi_out)
{
    __shared__ float psi_s[DLAT];
    __shared__ float wsum[2];

    const int shot = blockIdx.x;           // b*NK + k
    const int tid  = threadIdx.x;
    const int l = tid & 63, w = tid >> 6;
    const int h = l >> 5,  m = l & 31;     // half, lane-in-half

    // ---- z slice in registers (both halves load same addrs -> L1 broadcast)
    const float4* __restrict__ zb = (const float4*)(z + (size_t)shot * IN_DIM);
    const float4 za0 = zb[m], za1 = zb[m + 32], za2 = zb[m + 64], za3 = zb[m + 96];

    // ---- 16 rows per wave, 2 per pass (one per half); lane m<8 keeps row sums
    const int o0 = w * 16;
    float keep = 0.f;
    #pragma unroll 4
    for (int p = 0; p < 8; ++p) {
        const int r = o0 + p * 2 + h;
        const float4* __restrict__ wr = (const float4*)(W_proj + (size_t)r * IN_DIM);
        const float4 w0 = wr[m], w1 = wr[m + 32], w2 = wr[m + 64], w3 = wr[m + 96];
        float s = (w0.x * za0.x + w0.y * za0.y + w0.z * za0.z + w0.w * za0.w)
                + (w1.x * za1.x + w1.y * za1.y + w1.z * za1.z + w1.w * za1.w)
                + (w2.x * za2.x + w2.y * za2.y + w2.z * za2.z + w2.w * za2.w)
                + (w3.x * za3.x + w3.y * za3.y + w3.z * za3.z + w3.w * za3.w);
        s += __shfl_xor(s, 1);  s += __shfl_xor(s, 2);  s += __shfl_xor(s, 4);
        s += __shfl_xor(s, 8);  s += __shfl_xor(s, 16);     // stays in half
        if (m == p) keep = s;
    }
    if (m < 8) psi_s[o0 + 2 * m + h] = keep;
    __syncthreads();

    // ---- bias, ||psi||^2 (2 full waves), normalize, write
    float psi = 0.f;
    if (tid < 128) {
        psi = psi_s[tid] + b_proj[tid];
        float s = psi * psi;
        #pragma unroll
        for (int d = 32; d; d >>= 1) s += __shfl_xor(s, d);
        if ((tid & 63) == 0) wsum[tid >> 6] = s;
    }
    __syncthreads();
    if (tid < 128) {
        const float n2 = wsum[0] + wsum[1];
        psi_out[shot * DLAT + tid] =
            psi / fmaxf(sqrtf(n2), 1e-8f) * 0.35355339059327373f; // 1/sqrt(8)
    }
}

// ---------------------------------------------------------------------------
// Kernel M: one block per batch (32 x 256). Fully parallel: MLP partials via
// wave reduce, circulant mix in float4, ||y||^2 via wave reduce.  (R6 proven)
// ---------------------------------------------------------------------------
__global__ __launch_bounds__(256) void qsfm_mix(
    const float* __restrict__ t,
    const float* __restrict__ W1, const float* __restrict__ b1,
    const float* __restrict__ W2, const float* __restrict__ b2,
    const float* __restrict__ psi_norm,
    float* __restrict__ a_out, float* __restrict__ diag_out)
{
    __shared__ float ps[NK * 132];     // state, padded stride 132
    __shared__ float lamp[2];
    __shared__ float f_s[8];
    __shared__ float npart[4];

    const int b = blockIdx.x;
    const int tid = threadIdx.x;
    const int lane = tid & 63, w = tid >> 6;
    const int k = tid >> 5;            // shot of this thread's 4 elems
    const int e = (tid & 31) * 4;      // col base

    {   // stage state
        const float4 pv = ((const float4*)(psi_norm + (size_t)b * DTOT))[tid];
        *(float4*)(ps + k * 132 + e) = pv;
    }
    if (tid < 128) {                   // MLP partials, 2 full waves
        const float h = t[b] * W1[tid] + b1[tid];
        float ml = W2[tid] * (h / (1.f + expf(-h)));
        #pragma unroll
        for (int m = 32; m; m >>= 1) ml += __shfl_xor(ml, m);
        if (lane == 0) lamp[w] = ml;
    }
    __syncthreads();
    if (tid < 8) {
        // E = exp(-lam*H_idx): C8 circulant,
        // f(d) = 1/8 sum_m exp(-2 lam cos(pi m/4)) cos(pi m d/4)
        const float lam = tanhf(lamp[0] + lamp[1] + b2[0]) * 0.1f;
        const float c4[8] = {1.f, 0.70710678118654752f, 0.f, -0.70710678118654752f,
                             -1.f, -0.70710678118654752f, 0.f, 0.70710678118654752f};
        float a8 = 0.f;
        #pragma unroll
        for (int m = 0; m < 8; ++m)
            a8 += expf(-2.f * lam * c4[m]) * c4[(m * tid) & 7];
        f_s[tid] = 0.125f * a8;
    }
    __syncthreads();

    // y = kron(E, I_128) @ state, 4 elems per thread (float4)
    float4 y4 = {0.f, 0.f, 0.f, 0.f};
    #pragma unroll
    for (int kp = 0; kp < NK; ++kp) {
        const float fc = f_s[(k - kp) & 7];
        const float4 p4 = *(const float4*)(ps + kp * 132 + e);
        y4.x += fc * p4.x; y4.y += fc * p4.y;
        y4.z += fc * p4.z; y4.w += fc * p4.w;
    }
    {
        float s = (y4.x * y4.x + y4.y * y4.y) + (y4.z * y4.z + y4.w * y4.w);
        #pragma unroll
        for (int m = 32; m; m >>= 1) s += __shfl_xor(s, m);
        if (lane == 0) npart[w] = s;
    }
    __syncthreads();

    // out[i][j] = a_i a_j + delta_ij*1e-7/tr2; a = y/sqrt(n2c*tr2)
    const float n2  = (npart[0] + npart[1]) + (npart[2] + npart[3]);
    const float n2c = fmaxf(n2, 1e-8f);
    const float tr2 = n2 / n2c + (float)DTOT * 1e-7f;
    const float sc  = 1.f / sqrtf(n2c * tr2);
    float4 av;
    av.x = y4.x * sc; av.y = y4.y * sc; av.z = y4.z * sc; av.w = y4.w * sc;
    ((float4*)(a_out + (size_t)b * DTOT))[tid] = av;
    if (tid == 0) diag_out[b] = 1e-7f / tr2;
}

// ---------------------------------------------------------------------------
// Kernel O: out[b,i,j] = a[b,i]*a[b,j] (+ diag[b] on the diagonal).
// Pure streaming write of 128 MB; a (128 KB) stays L2-resident.
// ---------------------------------------------------------------------------
__global__ __launch_bounds__(256) void qsfm_outer(
    const float* __restrict__ a, const float* __restrict__ diag,
    float4* __restrict__ out)
{
    const int total4 = NB * DTOT * (DTOT / 4);     // 8388608
    const int stride = gridDim.x * blockDim.x;
    for (int idx4 = blockIdx.x * blockDim.x + threadIdx.x; idx4 < total4;
         idx4 += stride) {
        const int j4 = idx4 & (DTOT / 4 - 1);      // float4 col
        const int i  = (idx4 >> 8) & (DTOT - 1);   // row
        const int b  = idx4 >> 18;                 // / (1024*256)
        const float ai = a[b * DTOT + i];
        const float4 aj = *(const float4*)(a + b * DTOT + j4 * 4);
        float4 v;
        v.x = ai * aj.x; v.y = ai * aj.y; v.z = ai * aj.z; v.w = ai * aj.w;
        const int dj = i - j4 * 4;
        if (dj >= 0 && dj < 4) {
            const float dd = diag[b];
            if      (dj == 0) v.x += dd;
            else if (dj == 1) v.y += dd;
            else if (dj == 2) v.z += dd;
            else              v.w += dd;
        }
        out[idx4] = v;
    }
}

extern "C" void kernel_launch(void* const* d_in, const int* in_sizes, int n_in,
                              void* d_out, int out_size, void* d_ws, size_t ws_size,
                              hipStream_t stream) {
    (void)in_sizes; (void)n_in; (void)out_size; (void)ws_size;
    const float* z  = (const float*)d_in[0];
    const float* t  = (const float*)d_in[1];
    const float* Wp = (const float*)d_in[2];
    const float* bp = (const float*)d_in[3];
    const float* W1 = (const float*)d_in[4];
    const float* b1 = (const float*)d_in[5];
    const float* W2 = (const float*)d_in[6];
    const float* b2 = (const float*)d_in[7];

    float* ws       = (float*)d_ws;
    float* psi_norm = ws;                        // NB*DTOT floats
    float* a        = psi_norm + NB * DTOT;      // NB*DTOT floats
    float* diag     = a + NB * DTOT;             // NB floats

    qsfm_proj<<<NB * NK, 512, 0, stream>>>(z, Wp, bp, psi_norm);
    qsfm_mix<<<NB, 256, 0, stream>>>(t, W1, b1, W2, b2, psi_norm, a, diag);
    qsfm_outer<<<2048, 256, 0, stream>>>(a, diag, (float4*)d_out);
}

// Round 8
// 33.757 us; speedup vs baseline: 1.4710x; 1.0797x over previous
//
#include <hip/hip_runtime.h>

#define NB 32
#define NK 8
#define IN_DIM 512
#define DLAT 128
#define DTOT 1024

// ---------------------------------------------------------------------------
// Kernel P (R7-proven): one block per shot (256 blocks x 512 threads).
// z row in 4 float4 registers/lane; wave w owns rows [w*16,+16), 2 rows per
// pass in 32-lane halves; 5-step half-wave shuffle reduce. Writes normalized
// psi (pre-scaled by 1/sqrt(K)) to workspace.
// ---------------------------------------------------------------------------
__global__ __launch_bounds__(512) void qsfm_proj(
    const float* __restrict__ z, const float* __restrict__ W_proj,
    const float* __restrict__ b_proj, float* __restrict__ psi_out)
{
    __shared__ float psi_s[DLAT];
    __shared__ float wsum[2];

    const int shot = blockIdx.x;           // b*NK + k
    const int tid  = threadIdx.x;
    const int l = tid & 63, w = tid >> 6;
    const int h = l >> 5,  m = l & 31;     // half, lane-in-half

    const float4* __restrict__ zb = (const float4*)(z + (size_t)shot * IN_DIM);
    const float4 za0 = zb[m], za1 = zb[m + 32], za2 = zb[m + 64], za3 = zb[m + 96];

    const int o0 = w * 16;
    float keep = 0.f;
    #pragma unroll 4
    for (int p = 0; p < 8; ++p) {
        const int r = o0 + p * 2 + h;
        const float4* __restrict__ wr = (const float4*)(W_proj + (size_t)r * IN_DIM);
        const float4 w0 = wr[m], w1 = wr[m + 32], w2 = wr[m + 64], w3 = wr[m + 96];
        float s = (w0.x * za0.x + w0.y * za0.y + w0.z * za0.z + w0.w * za0.w)
                + (w1.x * za1.x + w1.y * za1.y + w1.z * za1.z + w1.w * za1.w)
                + (w2.x * za2.x + w2.y * za2.y + w2.z * za2.z + w2.w * za2.w)
                + (w3.x * za3.x + w3.y * za3.y + w3.z * za3.z + w3.w * za3.w);
        s += __shfl_xor(s, 1);  s += __shfl_xor(s, 2);  s += __shfl_xor(s, 4);
        s += __shfl_xor(s, 8);  s += __shfl_xor(s, 16);     // stays in half
        if (m == p) keep = s;
    }
    if (m < 8) psi_s[o0 + 2 * m + h] = keep;
    __syncthreads();

    float psi = 0.f;
    if (tid < 128) {
        psi = psi_s[tid] + b_proj[tid];
        float s = psi * psi;
        #pragma unroll
        for (int d = 32; d; d >>= 1) s += __shfl_xor(s, d);
        if ((tid & 63) == 0) wsum[tid >> 6] = s;
    }
    __syncthreads();
    if (tid < 128) {
        const float n2 = wsum[0] + wsum[1];
        psi_out[shot * DLAT + tid] =
            psi / fmaxf(sqrtf(n2), 1e-8f) * 0.35355339059327373f; // 1/sqrt(8)
    }
}

// ---------------------------------------------------------------------------
// Kernel MO: 2048 blocks x 256 threads; block g = (batch b = g>>6, slice
// s = g&63). Each block REDUNDANTLY computes its batch's mix (MLP ->
// circulant exp(-lam*H_idx) -> y -> n2 -> a in LDS; bitwise-deterministic
// across the 64 blocks of a batch, ~0.3 us, all 2048 blocks co-resident so
// this phase overlaps chip-wide), then writes rows [s*16, s*16+16) of
// out[b] = a a^T + diag*I.  The write is the bulk: 128 MiB streaming.
// ---------------------------------------------------------------------------
__global__ __launch_bounds__(256) void qsfm_mixouter(
    const float* __restrict__ t,
    const float* __restrict__ W1, const float* __restrict__ b1,
    const float* __restrict__ W2, const float* __restrict__ b2,
    const float* __restrict__ psi_norm,
    float4* __restrict__ out)
{
    __shared__ float ps[NK * 132];     // state, padded stride 132
    __shared__ float a_s[DTOT];        // rank-1 vector
    __shared__ float lamp[2];
    __shared__ float f_s[8];
    __shared__ float npart[4];
    __shared__ float diag_sh;

    const int g = blockIdx.x;
    const int b = g >> 6;              // batch
    const int s = g & 63;              // 16-row slice
    const int tid = threadIdx.x;
    const int lane = tid & 63, w = tid >> 6;
    const int k = tid >> 5;            // shot of this thread's 4 elems
    const int e = (tid & 31) * 4;      // col base

    {   // stage normalized state (4 KB, L2-resident)
        const float4 pv = ((const float4*)(psi_norm + (size_t)b * DTOT))[tid];
        *(float4*)(ps + k * 132 + e) = pv;
    }
    if (tid < 128) {                   // MLP partials, 2 full waves
        const float h = t[b] * W1[tid] + b1[tid];
        float ml = W2[tid] * (h / (1.f + expf(-h)));
        #pragma unroll
        for (int m = 32; m; m >>= 1) ml += __shfl_xor(ml, m);
        if (lane == 0) lamp[w] = ml;
    }
    __syncthreads();
    if (tid < 8) {
        // E = exp(-lam*H_idx): C8 circulant,
        // f(d) = 1/8 sum_m exp(-2 lam cos(pi m/4)) cos(pi m d/4)
        const float lam = tanhf(lamp[0] + lamp[1] + b2[0]) * 0.1f;
        const float c4[8] = {1.f, 0.70710678118654752f, 0.f, -0.70710678118654752f,
                             -1.f, -0.70710678118654752f, 0.f, 0.70710678118654752f};
        float a8 = 0.f;
        #pragma unroll
        for (int m = 0; m < 8; ++m)
            a8 += expf(-2.f * lam * c4[m]) * c4[(m * tid) & 7];
        f_s[tid] = 0.125f * a8;
    }
    __syncthreads();

    // y = kron(E, I_128) @ state, 4 elems per thread (float4)
    float4 y4 = {0.f, 0.f, 0.f, 0.f};
    #pragma unroll
    for (int kp = 0; kp < NK; ++kp) {
        const float fc = f_s[(k - kp) & 7];
        const float4 p4 = *(const float4*)(ps + kp * 132 + e);
        y4.x += fc * p4.x; y4.y += fc * p4.y;
        y4.z += fc * p4.z; y4.w += fc * p4.w;
    }
    {
        float q = (y4.x * y4.x + y4.y * y4.y) + (y4.z * y4.z + y4.w * y4.w);
        #pragma unroll
        for (int m = 32; m; m >>= 1) q += __shfl_xor(q, m);
        if (lane == 0) npart[w] = q;
    }
    __syncthreads();

    // a = y / sqrt(n2c*tr2); out[i][j] = a_i a_j + delta_ij * 1e-7/tr2
    const float n2  = (npart[0] + npart[1]) + (npart[2] + npart[3]);
    const float n2c = fmaxf(n2, 1e-8f);
    const float tr2 = n2 / n2c + (float)DTOT * 1e-7f;
    const float sc  = 1.f / sqrtf(n2c * tr2);
    float4 av;
    av.x = y4.x * sc; av.y = y4.y * sc; av.z = y4.z * sc; av.w = y4.w * sc;
    ((float4*)a_s)[tid] = av;
    if (tid == 0) diag_sh = 1e-7f / tr2;
    __syncthreads();

    // ---- write rows [s*16, +16): per row one LDS broadcast + 4 mul + store
    const float dd = diag_sh;
    const float4 aj = ((const float4*)a_s)[tid];   // hoisted: same all rows
    float4* __restrict__ outb =
        out + ((size_t)b << 18) + (size_t)(s * 16) * 256;
    #pragma unroll 4
    for (int it = 0; it < 16; ++it) {
        const int i = s * 16 + it;
        const float ai = a_s[i];                   // wave-uniform broadcast
        float4 v;
        v.x = ai * aj.x; v.y = ai * aj.y; v.z = ai * aj.z; v.w = ai * aj.w;
        const int dj = i - tid * 4;
        if (dj >= 0 && dj < 4) {
            if      (dj == 0) v.x += dd;
            else if (dj == 1) v.y += dd;
            else if (dj == 2) v.z += dd;
            else              v.w += dd;
        }
        outb[(size_t)it * 256 + tid] = v;
    }
}

extern "C" void kernel_launch(void* const* d_in, const int* in_sizes, int n_in,
                              void* d_out, int out_size, void* d_ws, size_t ws_size,
                              hipStream_t stream) {
    (void)in_sizes; (void)n_in; (void)out_size; (void)ws_size;
    const float* z  = (const float*)d_in[0];
    const float* t  = (const float*)d_in[1];
    const float* Wp = (const float*)d_in[2];
    const float* bp = (const float*)d_in[3];
    const float* W1 = (const float*)d_in[4];
    const float* b1 = (const float*)d_in[5];
    const float* W2 = (const float*)d_in[6];
    const float* b2 = (const float*)d_in[7];

    float* psi_norm = (float*)d_ws;              // NB*DTOT floats

    qsfm_proj<<<NB * NK, 512, 0, stream>>>(z, Wp, bp, psi_norm);
    qsfm_mixouter<<<2048, 256, 0, stream>>>(t, W1, b1, W2, b2, psi_norm,
                                            (float4*)d_out);
}